// Round 1
// baseline (857.846 us; speedup 1.0000x reference)
//
#include <hip/hip_runtime.h>

#define LRELU(v) ((v) >= 0.f ? (v) : 0.1f*(v))

constexpr int NN = 128;               // nodes per graph
constexpr int NB = 128;               // graphs
constexpr float GNORM = 1.0f/127.0f;  // dinv[src]*dinv[dst] on a complete graph
constexpr int SMAT[16] = {0,1,2,3,1,4,5,6,2,5,7,8,3,6,8,9};

// ---------------------------------------------------------------------------
// K1: GCN, closed form for complete graph: out_v = (S - (hW)_v)/127 + b
// one workgroup per graph, one thread per node
// ---------------------------------------------------------------------------
__global__ __launch_bounds__(128) void k_gcn(
    const float* __restrict__ x,
    const float* __restrict__ Wg0, const float* __restrict__ bg0,
    const float* __restrict__ Wg1, const float* __restrict__ bg1,
    const float* __restrict__ Wg2, const float* __restrict__ bg2,
    float* __restrict__ hout)
{
    __shared__ float w0[192], w1[1024], w2[2048];
    __shared__ float bb0[32], bb1[32], bb2[64];
    __shared__ float ta[128][65];
    __shared__ float tb[128][65];
    __shared__ float part[4][64];
    __shared__ float S[64];
    const int v = threadIdx.x;
    const int b = blockIdx.x;

    for (int idx = v; idx < 192;  idx += 128) w0[idx] = Wg0[idx];
    for (int idx = v; idx < 1024; idx += 128) w1[idx] = Wg1[idx];
    for (int idx = v; idx < 2048; idx += 128) w2[idx] = Wg2[idx];
    if (v < 32) { bb0[v] = bg0[v]; bb1[v] = bg1[v]; }
    if (v < 64) bb2[v] = bg2[v];

    float xv[6];
    #pragma unroll
    for (int k = 0; k < 6; ++k) xv[k] = x[(b*NN + v)*6 + k];
    __syncthreads();

    // ---- layer 0: t0 = x @ Wg0 (6->32) ----
    for (int n = 0; n < 32; ++n) {
        float acc = 0.f;
        #pragma unroll
        for (int k = 0; k < 6; ++k) acc += xv[k]*w0[k*32+n];
        ta[v][n] = acc;
    }
    __syncthreads();
    {   // column sums
        const int g = v >> 5, d = v & 31;
        float p = 0.f;
        for (int r = 0; r < 32; ++r) p += ta[g*32+r][d];
        part[g][d] = p;
    }
    __syncthreads();
    if (v < 32) S[v] = part[0][v]+part[1][v]+part[2][v]+part[3][v];
    __syncthreads();
    for (int n = 0; n < 32; ++n) {
        float h = (S[n] - ta[v][n])*GNORM + bb0[n];
        ta[v][n] = LRELU(h);
    }
    __syncthreads();

    // ---- layer 1: t1 = h1 @ Wg1 (32->32) ----
    for (int n = 0; n < 32; ++n) {
        float acc = 0.f;
        #pragma unroll
        for (int k = 0; k < 32; ++k) acc += ta[v][k]*w1[k*32+n];
        tb[v][n] = acc;
    }
    __syncthreads();
    {
        const int g = v >> 5, d = v & 31;
        float p = 0.f;
        for (int r = 0; r < 32; ++r) p += tb[g*32+r][d];
        part[g][d] = p;
    }
    __syncthreads();
    if (v < 32) S[v] = part[0][v]+part[1][v]+part[2][v]+part[3][v];
    __syncthreads();
    for (int n = 0; n < 32; ++n) {
        float h = (S[n] - tb[v][n])*GNORM + bb1[n];
        tb[v][n] = LRELU(h);
    }
    __syncthreads();

    // ---- layer 2: t2 = h2 @ Wg2 (32->64), no lrelu on output ----
    for (int n = 0; n < 64; ++n) {
        float acc = 0.f;
        #pragma unroll
        for (int k = 0; k < 32; ++k) acc += tb[v][k]*w2[k*64+n];
        ta[v][n] = acc;
    }
    __syncthreads();
    {
        const int g = v >> 5, d = v & 31;
        float p0 = 0.f, p1 = 0.f;
        for (int r = 0; r < 32; ++r) { p0 += ta[g*32+r][d]; p1 += ta[g*32+r][d+32]; }
        part[g][d] = p0; part[g][d+32] = p1;
    }
    __syncthreads();
    if (v < 64) S[v] = part[0][v]+part[1][v]+part[2][v]+part[3][v];
    __syncthreads();
    for (int n = 0; n < 64; ++n)
        hout[(b*NN + v)*64 + n] = (S[n] - ta[v][n])*GNORM + bb2[n];
}

// ---------------------------------------------------------------------------
// K2: node MLP v = (lrelu(lrelu(xb@Wn0+b)@Wn1+b))@Wn2+b ; write U diag blocks
// one thread per node, 64-thread blocks
// ---------------------------------------------------------------------------
__global__ __launch_bounds__(64) void k_nodemlp(
    const float* __restrict__ xb,
    const float* __restrict__ Wn0, const float* __restrict__ bn0,
    const float* __restrict__ Wn1, const float* __restrict__ bn1,
    const float* __restrict__ Wn2, const float* __restrict__ bn2,
    float* __restrict__ U)
{
    __shared__ float w0[4096], w1[4096], w2[640];
    __shared__ float bb0[64], bb1[64], bb2[16];
    __shared__ float ubuf[64][65], wbuf[64][65];
    const int tid  = threadIdx.x;
    const int node = blockIdx.x*64 + tid;
    const int b = node >> 7, i = node & 127;

    for (int idx = tid; idx < 4096; idx += 64) { w0[idx] = Wn0[idx]; w1[idx] = Wn1[idx]; }
    for (int idx = tid; idx < 640;  idx += 64) w2[idx] = Wn2[idx];
    bb0[tid] = bn0[tid]; bb1[tid] = bn1[tid];
    if (tid < 10) bb2[tid] = bn2[tid];

    float xv[64];
    #pragma unroll
    for (int k4 = 0; k4 < 16; ++k4) {
        float4 t = *(const float4*)(xb + node*64 + k4*4);
        xv[k4*4+0]=t.x; xv[k4*4+1]=t.y; xv[k4*4+2]=t.z; xv[k4*4+3]=t.w;
    }
    __syncthreads();

    for (int n = 0; n < 64; ++n) {
        float acc = bb0[n];
        #pragma unroll
        for (int k = 0; k < 64; ++k) acc += xv[k]*w0[k*64+n];
        ubuf[tid][n] = LRELU(acc);
    }
    for (int n = 0; n < 64; ++n) {
        float acc = bb1[n];
        #pragma unroll
        for (int k = 0; k < 64; ++k) acc += ubuf[tid][k]*w1[k*64+n];
        wbuf[tid][n] = LRELU(acc);
    }
    float vout[10];
    #pragma unroll
    for (int m = 0; m < 10; ++m) {
        float acc = bb2[m];
        #pragma unroll
        for (int k = 0; k < 64; ++k) acc += wbuf[tid][k]*w2[k*10+m];
        vout[m] = acc;
    }

    float* Ub = U + (size_t)b*262144 + (size_t)(4*i)*512 + 4*i;
    #pragma unroll
    for (int p = 0; p < 4; ++p) {
        float4 o;
        o.x = vout[SMAT[4*p+0]]; o.y = vout[SMAT[4*p+1]];
        o.z = vout[SMAT[4*p+2]]; o.w = vout[SMAT[4*p+3]];
        *(float4*)(Ub + p*512) = o;
    }
}

// ---------------------------------------------------------------------------
// K3: A = xb @ We0[0:64,:], Bt = xb @ We0[64:128,:]   (edge layer-0 factored)
// 16 nodes per 128-thread workgroup; thread owns one output column
// ---------------------------------------------------------------------------
__global__ __launch_bounds__(128) void k_ab(
    const float* __restrict__ xb,
    const float* __restrict__ We0,
    float* __restrict__ Aout, float* __restrict__ Bout)
{
    __shared__ float xs[16][64];
    const int tid  = threadIdx.x;
    const int base = blockIdx.x * 16;
    for (int idx = tid; idx < 1024; idx += 128)
        xs[idx>>6][idx&63] = xb[base*64 + idx];
    __syncthreads();

    float accA[16], accB[16];
    #pragma unroll
    for (int nd = 0; nd < 16; ++nd) { accA[nd] = 0.f; accB[nd] = 0.f; }
    for (int k = 0; k < 64; ++k) {
        const float wa = We0[k*128 + tid];
        const float wb = We0[(64+k)*128 + tid];
        #pragma unroll
        for (int nd = 0; nd < 16; ++nd) {
            const float xval = xs[nd][k];
            accA[nd] += xval*wa;
            accB[nd] += xval*wb;
        }
    }
    #pragma unroll
    for (int nd = 0; nd < 16; ++nd) {
        Aout[(base+nd)*128 + tid] = accA[nd];
        Bout[(base+nd)*128 + tid] = accB[nd];
    }
}

// ---------------------------------------------------------------------------
// K4: per-edge MLP (layers 1,2) + scatter into U, 64 edges per workgroup
// e0 = lrelu(A[i]+Bt[j]+be0) in LDS; e1 = lrelu(e0@We1+be1); e2 = e1@We2+be2
// ---------------------------------------------------------------------------
__global__ __launch_bounds__(256) void k_edge(
    const float* __restrict__ A, const float* __restrict__ Bt,
    const int* __restrict__ ud,
    const float* __restrict__ be0v,
    const float* __restrict__ We1, const float* __restrict__ be1v,
    const float* __restrict__ We2, const float* __restrict__ be2v,
    float* __restrict__ U)
{
    __shared__ __align__(16) float e0[64][132];
    __shared__ int ij[128];
    const int tid = threadIdx.x;
    const int b = blockIdx.x / 127;
    const int t = blockIdx.x % 127;
    if (tid < 128) ij[tid] = ud[t*128 + tid];
    __syncthreads();

    // phase 1: build e0 tile (64 edges x 128)
    {
        const int c4 = tid & 31;
        const int s0 = tid >> 5;
        const float4 bias = ((const float4*)be0v)[c4];
        #pragma unroll
        for (int r = 0; r < 8; ++r) {
            const int s = s0*8 + r;
            const int i = ij[2*s], j = ij[2*s+1];
            const float4 av = ((const float4*)(A  + (size_t)(b*128+i)*128))[c4];
            const float4 bv = ((const float4*)(Bt + (size_t)(b*128+j)*128))[c4];
            float4 e;
            e.x = LRELU(av.x+bv.x+bias.x);
            e.y = LRELU(av.y+bv.y+bias.y);
            e.z = LRELU(av.z+bv.z+bias.z);
            e.w = LRELU(av.w+bv.w+bias.w);
            *(float4*)(&e0[s][c4*4]) = e;
        }
    }
    __syncthreads();

    // phase 2: GEMM e0(64x128) @ We1(128x128), thread tile 8 rows x 4 cols
    const int tx = tid & 31, ty = tid >> 5;
    const int n0 = tx*4;
    float acc[8][4];
    #pragma unroll
    for (int r = 0; r < 8; ++r)
        { acc[r][0]=0.f; acc[r][1]=0.f; acc[r][2]=0.f; acc[r][3]=0.f; }

    for (int k = 0; k < 128; k += 4) {
        float w[4][4];
        #pragma unroll
        for (int kk = 0; kk < 4; ++kk) {
            const float4 t4 = *(const float4*)(We1 + (k+kk)*128 + n0);
            w[kk][0]=t4.x; w[kk][1]=t4.y; w[kk][2]=t4.z; w[kk][3]=t4.w;
        }
        #pragma unroll
        for (int r = 0; r < 8; ++r) {
            const float4 a4 = *(const float4*)(&e0[ty*8+r][k]);
            const float av[4] = {a4.x, a4.y, a4.z, a4.w};
            #pragma unroll
            for (int kk = 0; kk < 4; ++kk) {
                #pragma unroll
                for (int q = 0; q < 4; ++q)
                    acc[r][q] += av[kk]*w[kk][q];
            }
        }
    }

    // e1 = lrelu(acc + be1) back into the same LDS tile
    const float4 b1 = ((const float4*)be1v)[tx];
    __syncthreads();
    #pragma unroll
    for (int r = 0; r < 8; ++r) {
        float4 e;
        e.x = LRELU(acc[r][0]+b1.x);
        e.y = LRELU(acc[r][1]+b1.y);
        e.z = LRELU(acc[r][2]+b1.z);
        e.w = LRELU(acc[r][3]+b1.w);
        *(float4*)(&e0[ty*8+r][n0]) = e;
    }
    __syncthreads();

    // phase 3: e2 = e1 @ We2 + be2 ; write block (i,j) and mirror (j,i)
    const int p = tid & 3;
    const int s = tid >> 2;
    const int i = ij[2*s], j = ij[2*s+1];
    const float4 b2 = ((const float4*)be2v)[p];
    float acc2[4] = {b2.x, b2.y, b2.z, b2.w};
    for (int n = 0; n < 128; n += 4) {
        const float4 ev = *(const float4*)(&e0[s][n]);
        const float e_[4] = {ev.x, ev.y, ev.z, ev.w};
        #pragma unroll
        for (int nn = 0; nn < 4; ++nn) {
            const float4 wv = *(const float4*)(We2 + (n+nn)*16 + p*4);
            acc2[0] += e_[nn]*wv.x;
            acc2[1] += e_[nn]*wv.y;
            acc2[2] += e_[nn]*wv.z;
            acc2[3] += e_[nn]*wv.w;
        }
    }
    float4 out; out.x=acc2[0]; out.y=acc2[1]; out.z=acc2[2]; out.w=acc2[3];
    float* Ub = U + (size_t)b*262144;
    *(float4*)(Ub + (size_t)(4*i+p)*512 + 4*j) = out;
    *(float4*)(Ub + (size_t)(4*j+p)*512 + 4*i) = out;
}

// ---------------------------------------------------------------------------
extern "C" void kernel_launch(void* const* d_in, const int* in_sizes, int n_in,
                              void* d_out, int out_size, void* d_ws, size_t ws_size,
                              hipStream_t stream)
{
    const float* x   = (const float*)d_in[0];
    const int*   ud  = (const int*)  d_in[3];
    const float* Wg0 = (const float*)d_in[4];
    const float* bg0 = (const float*)d_in[5];
    const float* Wg1 = (const float*)d_in[6];
    const float* bg1 = (const float*)d_in[7];
    const float* Wg2 = (const float*)d_in[8];
    const float* bg2 = (const float*)d_in[9];
    const float* Wn0 = (const float*)d_in[10];
    const float* bn0 = (const float*)d_in[11];
    const float* Wn1 = (const float*)d_in[12];
    const float* bn1 = (const float*)d_in[13];
    const float* Wn2 = (const float*)d_in[14];
    const float* bn2 = (const float*)d_in[15];
    const float* We0 = (const float*)d_in[16];
    const float* be0 = (const float*)d_in[17];
    const float* We1 = (const float*)d_in[18];
    const float* be1 = (const float*)d_in[19];
    const float* We2 = (const float*)d_in[20];
    const float* be2 = (const float*)d_in[21];

    float* hout = (float*)d_out;                 // (16384, 64) == xb
    float* U    = (float*)d_out + 1048576;       // (128, 512, 512)
    float* Aw   = (float*)d_ws;                  // (16384, 128)
    float* Bw   = Aw + (size_t)16384*128;        // (16384, 128)

    k_gcn<<<dim3(128), dim3(128), 0, stream>>>(x, Wg0,bg0, Wg1,bg1, Wg2,bg2, hout);
    k_nodemlp<<<dim3(256), dim3(64), 0, stream>>>(hout, Wn0,bn0, Wn1,bn1, Wn2,bn2, U);
    k_ab<<<dim3(1024), dim3(128), 0, stream>>>(hout, We0, Aw, Bw);
    k_edge<<<dim3(128*127), dim3(256), 0, stream>>>(Aw, Bw, ud, be0, We1, be1, We2, be2, U);
}

// Round 2
// 731.028 us; speedup vs baseline: 1.1735x; 1.1735x over previous
//
#include <hip/hip_runtime.h>
#include <hip/hip_bf16.h>

#define LRELU(v) ((v) >= 0.f ? (v) : 0.1f*(v))

typedef float  f32x4 __attribute__((ext_vector_type(4)));
typedef short  s16x8 __attribute__((ext_vector_type(8)));
typedef unsigned short ushort_t;

constexpr float GNORM = 1.0f/127.0f;  // dinv[src]*dinv[dst] on complete graph

#define MFMA(d, a, b) d = __builtin_amdgcn_mfma_f32_16x16x32_bf16(a, b, d, 0, 0, 0)

__device__ __forceinline__ ushort_t f2bf(float v) {
    return __builtin_bit_cast(ushort_t, __float2bfloat16(v));
}
__device__ __forceinline__ float bf2f(ushort_t u) {
    return __builtin_bit_cast(float, (unsigned)u << 16);
}

// ---------------------------------------------------------------------------
// K1: GCN closed form (complete graph): out_v = (S - (hW)_v)/127 + b
// one WG per graph, one thread per node; activations live in registers
// ---------------------------------------------------------------------------
__global__ __launch_bounds__(128) void k_gcn(
    const float* __restrict__ x,
    const float* __restrict__ Wg0, const float* __restrict__ bg0,
    const float* __restrict__ Wg1, const float* __restrict__ bg1,
    const float* __restrict__ Wg2, const float* __restrict__ bg2,
    float* __restrict__ hout)
{
    __shared__ __align__(16) float w0[192], w1[1024], w2[2048];
    __shared__ float bb0[32], bb1[32], bb2[64];
    __shared__ float ta[128][65];
    __shared__ float part[4][64];
    __shared__ float S[64];
    const int v = threadIdx.x;
    const int b = blockIdx.x;

    for (int idx = v; idx < 192;  idx += 128) w0[idx] = Wg0[idx];
    for (int idx = v; idx < 1024; idx += 128) w1[idx] = Wg1[idx];
    for (int idx = v; idx < 2048; idx += 128) w2[idx] = Wg2[idx];
    if (v < 32) { bb0[v] = bg0[v]; bb1[v] = bg1[v]; }
    if (v < 64) bb2[v] = bg2[v];

    float xv[6];
    #pragma unroll
    for (int k = 0; k < 6; ++k) xv[k] = x[(b*128 + v)*6 + k];
    __syncthreads();

    // ---- layer 0: 6 -> 32 ----
    float t0[32];
    #pragma unroll
    for (int n = 0; n < 32; ++n) {
        float a = 0.f;
        #pragma unroll
        for (int k = 0; k < 6; ++k) a += xv[k]*w0[k*32+n];
        t0[n] = a;
        ta[v][n] = a;
    }
    __syncthreads();
    { const int g = v >> 5, d = v & 31;
      float p = 0.f;
      for (int r = 0; r < 32; ++r) p += ta[g*32+r][d];
      part[g][d] = p; }
    __syncthreads();
    if (v < 32) S[v] = part[0][v]+part[1][v]+part[2][v]+part[3][v];
    __syncthreads();
    float h1[32];
    #pragma unroll
    for (int n = 0; n < 32; ++n) {
        float hv = (S[n] - t0[n])*GNORM + bb0[n];
        h1[n] = LRELU(hv);
    }
    __syncthreads();

    // ---- layer 1: 32 -> 32 ----
    float t1[32];
    #pragma unroll
    for (int n = 0; n < 32; ++n) t1[n] = 0.f;
    for (int k = 0; k < 32; ++k) {
        const float hk = h1[k];
        #pragma unroll
        for (int n4 = 0; n4 < 8; ++n4) {
            const float4 w = *(const float4*)&w1[k*32 + n4*4];
            t1[n4*4+0] += hk*w.x; t1[n4*4+1] += hk*w.y;
            t1[n4*4+2] += hk*w.z; t1[n4*4+3] += hk*w.w;
        }
    }
    #pragma unroll
    for (int n = 0; n < 32; ++n) ta[v][n] = t1[n];
    __syncthreads();
    { const int g = v >> 5, d = v & 31;
      float p = 0.f;
      for (int r = 0; r < 32; ++r) p += ta[g*32+r][d];
      part[g][d] = p; }
    __syncthreads();
    if (v < 32) S[v] = part[0][v]+part[1][v]+part[2][v]+part[3][v];
    __syncthreads();
    float h2[32];
    #pragma unroll
    for (int n = 0; n < 32; ++n) {
        float hv = (S[n] - t1[n])*GNORM + bb1[n];
        h2[n] = LRELU(hv);
    }
    __syncthreads();

    // ---- layer 2: 32 -> 64, no lrelu ----
    float t2[64];
    #pragma unroll
    for (int n = 0; n < 64; ++n) t2[n] = 0.f;
    for (int k = 0; k < 32; ++k) {
        const float hk = h2[k];
        #pragma unroll
        for (int n4 = 0; n4 < 16; ++n4) {
            const float4 w = *(const float4*)&w2[k*64 + n4*4];
            t2[n4*4+0] += hk*w.x; t2[n4*4+1] += hk*w.y;
            t2[n4*4+2] += hk*w.z; t2[n4*4+3] += hk*w.w;
        }
    }
    #pragma unroll
    for (int n = 0; n < 64; ++n) ta[v][n] = t2[n];
    __syncthreads();
    { const int g = v >> 5, d = v & 31;
      float p0 = 0.f, p1 = 0.f;
      for (int r = 0; r < 32; ++r) { p0 += ta[g*32+r][d]; p1 += ta[g*32+r][d+32]; }
      part[g][d] = p0; part[g][d+32] = p1; }
    __syncthreads();
    if (v < 64) S[v] = part[0][v]+part[1][v]+part[2][v]+part[3][v];
    __syncthreads();
    float* hrow = hout + (size_t)(b*128 + v)*64;
    #pragma unroll
    for (int n4 = 0; n4 < 16; ++n4) {
        float4 o;
        o.x = (S[n4*4+0] - t2[n4*4+0])*GNORM + bb2[n4*4+0];
        o.y = (S[n4*4+1] - t2[n4*4+1])*GNORM + bb2[n4*4+1];
        o.z = (S[n4*4+2] - t2[n4*4+2])*GNORM + bb2[n4*4+2];
        o.w = (S[n4*4+3] - t2[n4*4+3])*GNORM + bb2[n4*4+3];
        *(float4*)(hrow + n4*4) = o;
    }
}

// ---------------------------------------------------------------------------
// K2: node MLP; wave-per-node, lane-per-column; writes U diagonal blocks
// ---------------------------------------------------------------------------
__global__ __launch_bounds__(256) void k_nodemlp(
    const float* __restrict__ xb,
    const float* __restrict__ Wn0, const float* __restrict__ bn0,
    const float* __restrict__ Wn1, const float* __restrict__ bn1,
    const float* __restrict__ Wn2, const float* __restrict__ bn2,
    float* __restrict__ U)
{
    __shared__ __align__(16) float w0[4096], w1[4096], w2[640];
    __shared__ float bb0[64], bb1[64];
    __shared__ float bb2[16];
    __shared__ float xin[4][64], t1[4][64], t2[4][64], vb[4][10];
    const int tid = threadIdx.x;
    const int wv = tid >> 6, lane = tid & 63;
    const int node = blockIdx.x*4 + wv;

    for (int idx = tid; idx < 1024; idx += 256) {
        ((float4*)w0)[idx] = ((const float4*)Wn0)[idx];
        ((float4*)w1)[idx] = ((const float4*)Wn1)[idx];
    }
    for (int idx = tid; idx < 160; idx += 256)
        ((float4*)w2)[idx] = ((const float4*)Wn2)[idx];
    if (tid < 64) bb0[tid] = bn0[tid];
    else if (tid < 128) bb1[tid-64] = bn1[tid-64];
    else if (tid < 138) bb2[tid-128] = bn2[tid-128];
    xin[wv][lane] = xb[(size_t)node*64 + lane];
    __syncthreads();

    float a = bb0[lane];
    for (int k = 0; k < 64; ++k) a += xin[wv][k]*w0[k*64 + lane];
    t1[wv][lane] = LRELU(a);
    __syncthreads();

    float c = bb1[lane];
    for (int k = 0; k < 64; ++k) c += t1[wv][k]*w1[k*64 + lane];
    t2[wv][lane] = LRELU(c);
    __syncthreads();

    if (lane < 10) {
        float o = bb2[lane];
        for (int k = 0; k < 64; ++k) o += t2[wv][k]*w2[k*10 + lane];
        vb[wv][lane] = o;
    }
    __syncthreads();

    if (lane < 16) {
        const int m = (int)((0x9863875265413210ull >> (4*lane)) & 15ull);
        const int b = node >> 7, i = node & 127;
        U[(size_t)b*262144 + (size_t)(4*i + (lane>>2))*512 + 4*i + (lane&3)] = vb[wv][m];
    }
}

// ---------------------------------------------------------------------------
// K3: A = xb @ We0[0:64,:], Bt = xb @ We0[64:128,:]  (edge layer-0 factored)
// ---------------------------------------------------------------------------
__global__ __launch_bounds__(128) void k_ab(
    const float* __restrict__ xb,
    const float* __restrict__ We0,
    float* __restrict__ Aout, float* __restrict__ Bout)
{
    __shared__ float xs[16][64];
    const int tid  = threadIdx.x;
    const int base = blockIdx.x * 16;
    for (int idx = tid; idx < 1024; idx += 128)
        xs[idx>>6][idx&63] = xb[(size_t)base*64 + idx];
    __syncthreads();

    float accA[16], accB[16];
    #pragma unroll
    for (int nd = 0; nd < 16; ++nd) { accA[nd] = 0.f; accB[nd] = 0.f; }
    for (int k = 0; k < 64; ++k) {
        const float wa = We0[k*128 + tid];
        const float wb = We0[(64+k)*128 + tid];
        #pragma unroll
        for (int nd = 0; nd < 16; ++nd) {
            const float xval = xs[nd][k];
            accA[nd] += xval*wa;
            accB[nd] += xval*wb;
        }
    }
    #pragma unroll
    for (int nd = 0; nd < 16; ++nd) {
        Aout[(size_t)(base+nd)*128 + tid] = accA[nd];
        Bout[(size_t)(base+nd)*128 + tid] = accB[nd];
    }
}

// ---------------------------------------------------------------------------
// K4: pre-split We1 into bf16 hi/mid/lo laid out in MFMA B-fragment order:
// off = ((cf*4 + kc)*64 + lane)*8 + e, lane holds B[k][col]:
//   col = cf*16 + (lane&15), k = kc*32 + (lane>>4)*8 + e
// ---------------------------------------------------------------------------
__global__ __launch_bounds__(256) void k_prep(
    const float* __restrict__ We1,
    ushort_t* __restrict__ BH, ushort_t* __restrict__ BM, ushort_t* __restrict__ BL)
{
    const int idx = blockIdx.x*256 + threadIdx.x;   // 0..16383
    const int k = idx >> 7, col = idx & 127;
    const float v = We1[idx];
    const ushort_t h = f2bf(v);            const float fh = bf2f(h);
    const float r1 = v - fh;
    const ushort_t m = f2bf(r1);           const float fm = bf2f(m);
    const ushort_t l = f2bf(r1 - fm);
    const int cf = col >> 4, kc = (k >> 5) & 3;
    const int ln = ((k >> 3) & 3)*16 + (col & 15);
    const int e  = k & 7;
    const int off = ((cf*4 + kc)*64 + ln)*8 + e;
    BH[off] = h; BM[off] = m; BL[off] = l;
}

// ---------------------------------------------------------------------------
// K5: per-edge MLP via MFMA (bf16 3-way split, 6 products = fp32-class error)
// 64-edge tiles; e0 hi/mid/lo in LDS; B-fragments of We1 in registers.
// Wave wv owns output cols [32wv, 32wv+32); computes all 64 rows.
// ---------------------------------------------------------------------------
__global__ __launch_bounds__(256, 3) void k_edge(
    const float* __restrict__ A, const float* __restrict__ Bt,
    const int* __restrict__ ud,
    const float* __restrict__ be0v,
    const ushort_t* __restrict__ BH, const ushort_t* __restrict__ BM,
    const ushort_t* __restrict__ BL,
    const float* __restrict__ be1v,
    const float* __restrict__ We2, const float* __restrict__ be2v,
    float* __restrict__ U)
{
    // eh/em/el: [64][136] ushort each (136 stride -> conflict-free b128 reads)
    __shared__ __align__(16) char smem[3*17408 + 512];
    ushort_t (*eh)[136] = (ushort_t(*)[136])(smem);
    ushort_t (*em)[136] = (ushort_t(*)[136])(smem + 17408);
    ushort_t (*el)[136] = (ushort_t(*)[136])(smem + 2*17408);
    int* ij = (int*)(smem + 3*17408);
    float* e1f = (float*)smem;             // [64][132] overlay for phase 3

    const int tid = threadIdx.x;
    const int wv = tid >> 6, lane = tid & 63;
    const int b = blockIdx.x / 127;
    const int t = blockIdx.x % 127;

    // --- B-fragments (We1 split) -> registers; independent of LDS, issue early
    s16x8 bh[2][4], bm[2][4], bl[2][4];
    #pragma unroll
    for (int c = 0; c < 2; ++c)
        #pragma unroll
        for (int kc = 0; kc < 4; ++kc) {
            const int off = (((wv*2 + c)*4 + kc)*64 + lane)*8;
            bh[c][kc] = *(const s16x8*)(BH + off);
            bm[c][kc] = *(const s16x8*)(BM + off);
            bl[c][kc] = *(const s16x8*)(BL + off);
        }

    if (tid < 128) ij[tid] = ud[t*128 + tid];
    __syncthreads();

    // --- phase 1: e0 = lrelu(A_i + Bt_j + be0), split to hi/mid/lo bf16
    {
        const int s  = tid >> 2;
        const int c0 = (tid & 3) * 32;
        const int i  = ij[2*s], jn = ij[2*s+1];
        const float* Ar = A  + (size_t)(b*128 + i )*128 + c0;
        const float* Br = Bt + (size_t)(b*128 + jn)*128 + c0;
        ushort_t hb[32], mb[32], lb[32];
        #pragma unroll
        for (int q = 0; q < 8; ++q) {
            const float4 av = ((const float4*)Ar)[q];
            const float4 bv = ((const float4*)Br)[q];
            const float4 bias = ((const float4*)be0v)[c0/4 + q];
            float vs[4] = {av.x+bv.x+bias.x, av.y+bv.y+bias.y,
                           av.z+bv.z+bias.z, av.w+bv.w+bias.w};
            #pragma unroll
            for (int e = 0; e < 4; ++e) {
                const float v = LRELU(vs[e]);
                const ushort_t h = f2bf(v);      const float fh = bf2f(h);
                const float r1 = v - fh;
                const ushort_t m = f2bf(r1);     const float fm = bf2f(m);
                hb[q*4+e] = h; mb[q*4+e] = m; lb[q*4+e] = f2bf(r1 - fm);
            }
        }
        #pragma unroll
        for (int q = 0; q < 4; ++q) {
            *(s16x8*)&eh[s][c0 + q*8] = *(const s16x8*)&hb[q*8];
            *(s16x8*)&em[s][c0 + q*8] = *(const s16x8*)&mb[q*8];
            *(s16x8*)&el[s][c0 + q*8] = *(const s16x8*)&lb[q*8];
        }
    }
    __syncthreads();

    // --- phase 2: e1 = e0 @ We1 via MFMA (6-term split product)
    f32x4 acc[4][2];
    #pragma unroll
    for (int rf = 0; rf < 4; ++rf)
        #pragma unroll
        for (int c = 0; c < 2; ++c)
            acc[rf][c] = (f32x4){0.f, 0.f, 0.f, 0.f};

    const int arow = lane & 15;
    const int ak   = (lane >> 4) * 8;
    #pragma unroll
    for (int kc = 0; kc < 4; ++kc) {
        const int kb = kc*32 + ak;
        #pragma unroll
        for (int rf = 0; rf < 4; ++rf) {
            const int r = rf*16 + arow;
            const s16x8 ah = *(const s16x8*)&eh[r][kb];
            const s16x8 am = *(const s16x8*)&em[r][kb];
            const s16x8 al = *(const s16x8*)&el[r][kb];
            #pragma unroll
            for (int c = 0; c < 2; ++c) {
                MFMA(acc[rf][c], ah, bh[c][kc]);
                MFMA(acc[rf][c], ah, bm[c][kc]);
                MFMA(acc[rf][c], am, bh[c][kc]);
                MFMA(acc[rf][c], am, bm[c][kc]);
                MFMA(acc[rf][c], ah, bl[c][kc]);
                MFMA(acc[rf][c], al, bh[c][kc]);
            }
        }
    }
    __syncthreads();   // all LDS reads of eh/em/el complete before overlay

    // --- e1 = lrelu(acc + be1) -> LDS (fp32), C-frag layout:
    //     col = 32wv + 16c + (lane&15), row = 16rf + (lane>>4)*4 + r
    {
        const int crow = (lane >> 4) * 4;
        const int ccol = lane & 15;
        #pragma unroll
        for (int c = 0; c < 2; ++c) {
            const int col = wv*32 + c*16 + ccol;
            const float b1 = be1v[col];
            #pragma unroll
            for (int rf = 0; rf < 4; ++rf)
                #pragma unroll
                for (int r = 0; r < 4; ++r) {
                    const float vv = acc[rf][c][r] + b1;
                    e1f[(rf*16 + crow + r)*132 + col] = LRELU(vv);
                }
        }
    }
    __syncthreads();

    // --- phase 3: e2 = e1 @ We2 + be2; write block (i,j) and mirror (j,i)
    {
        const int p = tid & 3;
        const int s = tid >> 2;
        const int i = ij[2*s], jn = ij[2*s+1];
        const float4 b2 = ((const float4*)be2v)[p];
        float acc2[4] = {b2.x, b2.y, b2.z, b2.w};
        const float* e1row = e1f + s*132;
        for (int n = 0; n < 128; n += 4) {
            const float4 ev = *(const float4*)(e1row + n);
            const float e_[4] = {ev.x, ev.y, ev.z, ev.w};
            #pragma unroll
            for (int nn = 0; nn < 4; ++nn) {
                const float4 wvv = *(const float4*)(We2 + (n+nn)*16 + p*4);
                acc2[0] += e_[nn]*wvv.x;
                acc2[1] += e_[nn]*wvv.y;
                acc2[2] += e_[nn]*wvv.z;
                acc2[3] += e_[nn]*wvv.w;
            }
        }
        float4 out; out.x = acc2[0]; out.y = acc2[1]; out.z = acc2[2]; out.w = acc2[3];
        float* Ub = U + (size_t)b*262144;
        *(float4*)(Ub + (size_t)(4*i + p)*512 + 4*jn) = out;
        *(float4*)(Ub + (size_t)(4*jn + p)*512 + 4*i) = out;
    }
}

// ---------------------------------------------------------------------------
extern "C" void kernel_launch(void* const* d_in, const int* in_sizes, int n_in,
                              void* d_out, int out_size, void* d_ws, size_t ws_size,
                              hipStream_t stream)
{
    const float* x   = (const float*)d_in[0];
    const int*   ud  = (const int*)  d_in[3];
    const float* Wg0 = (const float*)d_in[4];
    const float* bg0 = (const float*)d_in[5];
    const float* Wg1 = (const float*)d_in[6];
    const float* bg1 = (const float*)d_in[7];
    const float* Wg2 = (const float*)d_in[8];
    const float* bg2 = (const float*)d_in[9];
    const float* Wn0 = (const float*)d_in[10];
    const float* bn0 = (const float*)d_in[11];
    const float* Wn1 = (const float*)d_in[12];
    const float* bn1 = (const float*)d_in[13];
    const float* Wn2 = (const float*)d_in[14];
    const float* bn2 = (const float*)d_in[15];
    const float* We0 = (const float*)d_in[16];
    const float* be0 = (const float*)d_in[17];
    const float* We1 = (const float*)d_in[18];
    const float* be1 = (const float*)d_in[19];
    const float* We2 = (const float*)d_in[20];
    const float* be2 = (const float*)d_in[21];

    float* hout = (float*)d_out;                 // (16384, 64) == xb
    float* U    = (float*)d_out + 1048576;       // (128, 512, 512)
    float* Aw   = (float*)d_ws;                  // (16384, 128)
    float* Bw   = Aw + (size_t)16384*128;        // (16384, 128)
    ushort_t* BH = (ushort_t*)((char*)d_ws + (size_t)2*16384*128*4);
    ushort_t* BM = BH + 16384;
    ushort_t* BL = BM + 16384;

    k_gcn<<<dim3(128), dim3(128), 0, stream>>>(x, Wg0,bg0, Wg1,bg1, Wg2,bg2, hout);
    k_prep<<<dim3(64), dim3(256), 0, stream>>>(We1, BH, BM, BL);
    k_ab<<<dim3(1024), dim3(128), 0, stream>>>(hout, We0, Aw, Bw);
    k_edge<<<dim3(128*127), dim3(256), 0, stream>>>(Aw, Bw, ud, be0,
                                                    BH, BM, BL, be1, We2, be2, U);
    k_nodemlp<<<dim3(4096), dim3(256), 0, stream>>>(hout, Wn0,bn0, Wn1,bn1, Wn2,bn2, U);
}

// Round 3
// 419.078 us; speedup vs baseline: 2.0470x; 1.7444x over previous
//
#include <hip/hip_runtime.h>
#include <hip/hip_bf16.h>

#define LRELU(v) ((v) >= 0.f ? (v) : 0.1f*(v))

typedef float  f32x4 __attribute__((ext_vector_type(4)));
typedef short  s16x8 __attribute__((ext_vector_type(8)));
typedef int    i32x4 __attribute__((ext_vector_type(4)));
typedef unsigned short ushort_t;
typedef unsigned int   u32;

constexpr float GNORM = 1.0f/127.0f;  // dinv[src]*dinv[dst] on complete graph

#define MFMA(d, a, b) d = __builtin_amdgcn_mfma_f32_16x16x32_bf16(a, b, d, 0, 0, 0)

__device__ __forceinline__ ushort_t f2bf(float v) {
    return __builtin_bit_cast(ushort_t, __float2bfloat16(v));
}
__device__ __forceinline__ float bf2f(ushort_t u) {
    return __builtin_bit_cast(float, (u32)u << 16);
}

// ---------------------------------------------------------------------------
// K1: GCN closed form (complete graph): out_v = (S - (hW)_v)/127 + b
// ---------------------------------------------------------------------------
__global__ __launch_bounds__(128) void k_gcn(
    const float* __restrict__ x,
    const float* __restrict__ Wg0, const float* __restrict__ bg0,
    const float* __restrict__ Wg1, const float* __restrict__ bg1,
    const float* __restrict__ Wg2, const float* __restrict__ bg2,
    float* __restrict__ hout)
{
    __shared__ __align__(16) float w0[192], w1[1024], w2[2048];
    __shared__ float bb0[32], bb1[32], bb2[64];
    __shared__ float ta[128][65];
    __shared__ float part[4][64];
    __shared__ float S[64];
    const int v = threadIdx.x;
    const int b = blockIdx.x;

    for (int idx = v; idx < 192;  idx += 128) w0[idx] = Wg0[idx];
    for (int idx = v; idx < 1024; idx += 128) w1[idx] = Wg1[idx];
    for (int idx = v; idx < 2048; idx += 128) w2[idx] = Wg2[idx];
    if (v < 32) { bb0[v] = bg0[v]; bb1[v] = bg1[v]; }
    if (v < 64) bb2[v] = bg2[v];

    float xv[6];
    #pragma unroll
    for (int k = 0; k < 6; ++k) xv[k] = x[(b*128 + v)*6 + k];
    __syncthreads();

    // ---- layer 0: 6 -> 32 ----
    float t0[32];
    #pragma unroll
    for (int n = 0; n < 32; ++n) {
        float a = 0.f;
        #pragma unroll
        for (int k = 0; k < 6; ++k) a += xv[k]*w0[k*32+n];
        t0[n] = a;
        ta[v][n] = a;
    }
    __syncthreads();
    { const int g = v >> 5, d = v & 31;
      float p = 0.f;
      for (int r = 0; r < 32; ++r) p += ta[g*32+r][d];
      part[g][d] = p; }
    __syncthreads();
    if (v < 32) S[v] = part[0][v]+part[1][v]+part[2][v]+part[3][v];
    __syncthreads();
    float h1[32];
    #pragma unroll
    for (int n = 0; n < 32; ++n) {
        float hv = (S[n] - t0[n])*GNORM + bb0[n];
        h1[n] = LRELU(hv);
    }
    __syncthreads();

    // ---- layer 1: 32 -> 32 ----
    float t1[32];
    #pragma unroll
    for (int n = 0; n < 32; ++n) t1[n] = 0.f;
    for (int k = 0; k < 32; ++k) {
        const float hk = h1[k];
        #pragma unroll
        for (int n4 = 0; n4 < 8; ++n4) {
            const float4 w = *(const float4*)&w1[k*32 + n4*4];
            t1[n4*4+0] += hk*w.x; t1[n4*4+1] += hk*w.y;
            t1[n4*4+2] += hk*w.z; t1[n4*4+3] += hk*w.w;
        }
    }
    #pragma unroll
    for (int n = 0; n < 32; ++n) ta[v][n] = t1[n];
    __syncthreads();
    { const int g = v >> 5, d = v & 31;
      float p = 0.f;
      for (int r = 0; r < 32; ++r) p += ta[g*32+r][d];
      part[g][d] = p; }
    __syncthreads();
    if (v < 32) S[v] = part[0][v]+part[1][v]+part[2][v]+part[3][v];
    __syncthreads();
    float h2[32];
    #pragma unroll
    for (int n = 0; n < 32; ++n) {
        float hv = (S[n] - t1[n])*GNORM + bb1[n];
        h2[n] = LRELU(hv);
    }
    __syncthreads();

    // ---- layer 2: 32 -> 64 ----
    float t2[64];
    #pragma unroll
    for (int n = 0; n < 64; ++n) t2[n] = 0.f;
    for (int k = 0; k < 32; ++k) {
        const float hk = h2[k];
        #pragma unroll
        for (int n4 = 0; n4 < 16; ++n4) {
            const float4 w = *(const float4*)&w2[k*64 + n4*4];
            t2[n4*4+0] += hk*w.x; t2[n4*4+1] += hk*w.y;
            t2[n4*4+2] += hk*w.z; t2[n4*4+3] += hk*w.w;
        }
    }
    #pragma unroll
    for (int n = 0; n < 64; ++n) ta[v][n] = t2[n];
    __syncthreads();
    { const int g = v >> 5, d = v & 31;
      float p0 = 0.f, p1 = 0.f;
      for (int r = 0; r < 32; ++r) { p0 += ta[g*32+r][d]; p1 += ta[g*32+r][d+32]; }
      part[g][d] = p0; part[g][d+32] = p1; }
    __syncthreads();
    if (v < 64) S[v] = part[0][v]+part[1][v]+part[2][v]+part[3][v];
    __syncthreads();
    float* hrow = hout + (size_t)(b*128 + v)*64;
    #pragma unroll
    for (int n4 = 0; n4 < 16; ++n4) {
        float4 o;
        o.x = (S[n4*4+0] - t2[n4*4+0])*GNORM + bb2[n4*4+0];
        o.y = (S[n4*4+1] - t2[n4*4+1])*GNORM + bb2[n4*4+1];
        o.z = (S[n4*4+2] - t2[n4*4+2])*GNORM + bb2[n4*4+2];
        o.w = (S[n4*4+3] - t2[n4*4+3])*GNORM + bb2[n4*4+3];
        *(float4*)(hrow + n4*4) = o;
    }
}

// ---------------------------------------------------------------------------
// K2: node MLP; wave-per-node; writes U diagonal blocks
// ---------------------------------------------------------------------------
__global__ __launch_bounds__(256) void k_nodemlp(
    const float* __restrict__ xb,
    const float* __restrict__ Wn0, const float* __restrict__ bn0,
    const float* __restrict__ Wn1, const float* __restrict__ bn1,
    const float* __restrict__ Wn2, const float* __restrict__ bn2,
    float* __restrict__ U)
{
    __shared__ __align__(16) float w0[4096], w1[4096], w2[640];
    __shared__ float bb0[64], bb1[64];
    __shared__ float bb2[16];
    __shared__ float xin[4][64], t1[4][64], t2[4][64], vb[4][10];
    const int tid = threadIdx.x;
    const int wv = tid >> 6, lane = tid & 63;
    const int node = blockIdx.x*4 + wv;

    for (int idx = tid; idx < 1024; idx += 256) {
        ((float4*)w0)[idx] = ((const float4*)Wn0)[idx];
        ((float4*)w1)[idx] = ((const float4*)Wn1)[idx];
    }
    for (int idx = tid; idx < 160; idx += 256)
        ((float4*)w2)[idx] = ((const float4*)Wn2)[idx];
    if (tid < 64) bb0[tid] = bn0[tid];
    else if (tid < 128) bb1[tid-64] = bn1[tid-64];
    else if (tid < 138) bb2[tid-128] = bn2[tid-128];
    xin[wv][lane] = xb[(size_t)node*64 + lane];
    __syncthreads();

    float a = bb0[lane];
    for (int k = 0; k < 64; ++k) a += xin[wv][k]*w0[k*64 + lane];
    t1[wv][lane] = LRELU(a);
    __syncthreads();

    float c = bb1[lane];
    for (int k = 0; k < 64; ++k) c += t1[wv][k]*w1[k*64 + lane];
    t2[wv][lane] = LRELU(c);
    __syncthreads();

    if (lane < 10) {
        float o = bb2[lane];
        for (int k = 0; k < 64; ++k) o += t2[wv][k]*w2[k*10 + lane];
        vb[wv][lane] = o;
    }
    __syncthreads();

    if (lane < 16) {
        const int m = (int)((0x9863875265413210ull >> (4*lane)) & 15ull);
        const int b = node >> 7, i = node & 127;
        U[(size_t)b*262144 + (size_t)(4*i + (lane>>2))*512 + 4*i + (lane&3)] = vb[wv][m];
    }
}

// ---------------------------------------------------------------------------
// K3: A = xb @ We0[0:64,:], Bt = xb @ We0[64:128,:]
// ---------------------------------------------------------------------------
__global__ __launch_bounds__(128) void k_ab(
    const float* __restrict__ xb,
    const float* __restrict__ We0,
    float* __restrict__ Aout, float* __restrict__ Bout)
{
    __shared__ float xs[16][64];
    const int tid  = threadIdx.x;
    const int base = blockIdx.x * 16;
    for (int idx = tid; idx < 1024; idx += 128)
        xs[idx>>6][idx&63] = xb[(size_t)base*64 + idx];
    __syncthreads();

    float accA[16], accB[16];
    #pragma unroll
    for (int nd = 0; nd < 16; ++nd) { accA[nd] = 0.f; accB[nd] = 0.f; }
    for (int k = 0; k < 64; ++k) {
        const float wa = We0[k*128 + tid];
        const float wb = We0[(64+k)*128 + tid];
        #pragma unroll
        for (int nd = 0; nd < 16; ++nd) {
            const float xval = xs[nd][k];
            accA[nd] += xval*wa;
            accB[nd] += xval*wb;
        }
    }
    #pragma unroll
    for (int nd = 0; nd < 16; ++nd) {
        Aout[(size_t)(base+nd)*128 + tid] = accA[nd];
        Bout[(size_t)(base+nd)*128 + tid] = accB[nd];
    }
}

// ---------------------------------------------------------------------------
// K4: pre-split We1 (hi/mid bf16) into MFMA B-fragment order, and We2 too.
// We1 frag: off = ((cf*4+kc)*64 + ln)*8 + e ; lane ln holds B[k][col]:
//   col = cf*16 + (ln&15), k = kc*32 + (ln>>4)*8 + e
// We2 frag: off = (kc*64 + ln)*8 + e  (single 16-col fragment)
// ---------------------------------------------------------------------------
__global__ __launch_bounds__(256) void k_prep(
    const float* __restrict__ We1, const float* __restrict__ We2,
    ushort_t* __restrict__ BH, ushort_t* __restrict__ BM,
    ushort_t* __restrict__ W2H, ushort_t* __restrict__ W2M)
{
    const int gid = blockIdx.x*256 + threadIdx.x;
    if (gid < 16384) {
        const int k = gid >> 7, col = gid & 127;
        const float v = We1[gid];
        const ushort_t h = f2bf(v);
        const ushort_t m = f2bf(v - bf2f(h));
        const int cf = col >> 4, kc = (k >> 5) & 3;
        const int ln = ((k >> 3) & 3)*16 + (col & 15);
        const int e  = k & 7;
        const int off = ((cf*4 + kc)*64 + ln)*8 + e;
        BH[off] = h; BM[off] = m;
    }
    const int g2 = gid - 16384;
    if (g2 >= 0 && g2 < 2048) {
        const int k = g2 >> 4, n = g2 & 15;
        const float v = We2[g2];
        const ushort_t h = f2bf(v);
        const ushort_t m = f2bf(v - bf2f(h));
        const int kc = k >> 5;
        const int ln = ((k >> 3) & 3)*16 + n;
        const int e  = k & 7;
        const int off = (kc*64 + ln)*8 + e;
        W2H[off] = h; W2M[off] = m;
    }
}

// ---------------------------------------------------------------------------
// K5: per-edge MLP, fully MFMA (3-product bf16 split ~= fp32 accuracy).
// 64-edge tiles, 4 waves. LDS: eh[64]x256B, em[64]x256B, XOR-swizzled
// (byte ^= (row&7)<<4); phase-3 overlays the same 32KB as packed-u32 e1.
// ---------------------------------------------------------------------------
__global__ __launch_bounds__(256, 4) void k_edge(
    const float* __restrict__ A, const float* __restrict__ Bt,
    const int* __restrict__ ud,
    const float* __restrict__ be0v,
    const ushort_t* __restrict__ BH, const ushort_t* __restrict__ BM,
    const float* __restrict__ be1v,
    const ushort_t* __restrict__ W2H, const ushort_t* __restrict__ W2M,
    const float* __restrict__ be2v,
    float* __restrict__ U)
{
    __shared__ __align__(16) char smem[32768];   // eh: [0,16K), em: [16K,32K)
    const int tid = threadIdx.x;
    const int wv = tid >> 6, lane = tid & 63;
    const int b = blockIdx.x / 127;
    const int t = blockIdx.x - b*127;
    const int* ud2 = ud + t*128;

    // --- phase 1: e0 = lrelu(A_i + Bt_j + be0); split hi/mid -> LDS swizzled
    {
        const int s = lane;                    // edge row within tile
        const int i  = ud2[2*s], jn = ud2[2*s+1];
        const int c0 = wv*32;
        const float* Ar = A  + (size_t)(b*128 + i )*128 + c0;
        const float* Br = Bt + (size_t)(b*128 + jn)*128 + c0;
        const int sw = (s & 7) << 4;
        char* rowh = smem + s*256;
        #pragma unroll
        for (int q = 0; q < 4; ++q) {
            const float4 a0 = ((const float4*)Ar)[2*q];
            const float4 a1 = ((const float4*)Ar)[2*q+1];
            const float4 b0 = ((const float4*)Br)[2*q];
            const float4 b1 = ((const float4*)Br)[2*q+1];
            const float4 e0 = ((const float4*)be0v)[wv*8 + 2*q];
            const float4 e1 = ((const float4*)be0v)[wv*8 + 2*q + 1];
            float vs[8] = {a0.x+b0.x+e0.x, a0.y+b0.y+e0.y, a0.z+b0.z+e0.z, a0.w+b0.w+e0.w,
                           a1.x+b1.x+e1.x, a1.y+b1.y+e1.y, a1.z+b1.z+e1.z, a1.w+b1.w+e1.w};
            ushort_t hb[8], mb[8];
            #pragma unroll
            for (int e = 0; e < 8; ++e) {
                const float v = LRELU(vs[e]);
                const ushort_t h = f2bf(v);
                hb[e] = h;
                mb[e] = f2bf(v - bf2f(h));
            }
            const int off = (64*wv + 16*q) ^ sw;
            *(s16x8*)(rowh + off)         = *(const s16x8*)hb;
            *(s16x8*)(rowh + 16384 + off) = *(const s16x8*)mb;
        }
    }
    __syncthreads();

    // --- phase 2: e1 = e0 @ We1 (3-product). Wave wv: cols [32wv, 32wv+32)
    f32x4 acc[4][2];
    #pragma unroll
    for (int rf = 0; rf < 4; ++rf) {
        acc[rf][0] = (f32x4){0.f,0.f,0.f,0.f};
        acc[rf][1] = (f32x4){0.f,0.f,0.f,0.f};
    }
    {
        const int arow = lane & 15;
        const int klo  = (lane >> 4) * 16;     // byte offset of this lane's k-slice
        #pragma unroll
        for (int kc = 0; kc < 4; ++kc) {
            s16x8 bh[2], bm[2];
            #pragma unroll
            for (int c = 0; c < 2; ++c) {
                const int boff = (((wv*2 + c)*4 + kc)*64 + lane)*8;
                bh[c] = *(const s16x8*)(BH + boff);
                bm[c] = *(const s16x8*)(BM + boff);
            }
            const int kb = kc*64 + klo;
            #pragma unroll
            for (int rf = 0; rf < 4; ++rf) {
                const int row = rf*16 + arow;
                const int off = row*256 + (kb ^ ((row & 7) << 4));
                const s16x8 ah = *(const s16x8*)(smem + off);
                const s16x8 am = *(const s16x8*)(smem + 16384 + off);
                MFMA(acc[rf][0], ah, bh[0]);
                MFMA(acc[rf][0], ah, bm[0]);
                MFMA(acc[rf][0], am, bh[0]);
                MFMA(acc[rf][1], ah, bh[1]);
                MFMA(acc[rf][1], ah, bm[1]);
                MFMA(acc[rf][1], am, bh[1]);
            }
        }
    }
    __syncthreads();   // eh/em reads done; safe to overlay e1

    // --- e1 = lrelu(acc + be1) split hi/mid, packed (m<<16|h) u32 -> LDS
    // layout: row*512 + ((col*4) ^ ((row&7)<<4))
    {
        const int ccol = lane & 15;
        const int crow = (lane >> 4) * 4;
        #pragma unroll
        for (int c = 0; c < 2; ++c) {
            const int col = wv*32 + c*16 + ccol;
            const float b1 = be1v[col];
            const int col4 = col*4;
            #pragma unroll
            for (int rf = 0; rf < 4; ++rf) {
                #pragma unroll
                for (int r = 0; r < 4; ++r) {
                    const int row = rf*16 + crow + r;
                    const float v = LRELU(acc[rf][c][r] + b1);
                    const ushort_t h = f2bf(v);
                    const ushort_t m = f2bf(v - bf2f(h));
                    const u32 word = ((u32)m << 16) | (u32)h;
                    *(u32*)(smem + row*512 + (col4 ^ ((row & 7) << 4))) = word;
                }
            }
        }
    }
    __syncthreads();

    // --- phase 3: e2 = e1 @ We2 + be2 via MFMA; wave wv: rows [16wv,16wv+16)
    {
        const int row = wv*16 + (lane & 15);
        const int sw  = (row & 7) << 4;
        const char* rb = smem + row*512;
        f32x4 acc2 = (f32x4){0.f,0.f,0.f,0.f};
        #pragma unroll
        for (int kc = 0; kc < 4; ++kc) {
            const int kb = kc*128 + (lane >> 4)*32;
            const i32x4 w0 = *(const i32x4*)(rb + (kb ^ sw));
            const i32x4 w1 = *(const i32x4*)(rb + ((kb + 16) ^ sw));
            i32x4 hv, mv;
            hv[0] = (int)__builtin_amdgcn_perm((u32)w0[1], (u32)w0[0], 0x05040100u);
            hv[1] = (int)__builtin_amdgcn_perm((u32)w0[3], (u32)w0[2], 0x05040100u);
            hv[2] = (int)__builtin_amdgcn_perm((u32)w1[1], (u32)w1[0], 0x05040100u);
            hv[3] = (int)__builtin_amdgcn_perm((u32)w1[3], (u32)w1[2], 0x05040100u);
            mv[0] = (int)__builtin_amdgcn_perm((u32)w0[1], (u32)w0[0], 0x07060302u);
            mv[1] = (int)__builtin_amdgcn_perm((u32)w0[3], (u32)w0[2], 0x07060302u);
            mv[2] = (int)__builtin_amdgcn_perm((u32)w1[1], (u32)w1[0], 0x07060302u);
            mv[3] = (int)__builtin_amdgcn_perm((u32)w1[3], (u32)w1[2], 0x07060302u);
            const s16x8 ah = __builtin_bit_cast(s16x8, hv);
            const s16x8 am = __builtin_bit_cast(s16x8, mv);
            const int woff = (kc*64 + lane)*8;
            const s16x8 wh = *(const s16x8*)(W2H + woff);
            const s16x8 wm = *(const s16x8*)(W2M + woff);
            MFMA(acc2, ah, wh);
            MFMA(acc2, ah, wm);
            MFMA(acc2, am, wh);
        }
        const int col = lane & 15;
        const float b2 = be2v[col];
        const int p = col >> 2, q = col & 3;
        float* Ub = U + (size_t)b*262144;
        #pragma unroll
        for (int r = 0; r < 4; ++r) {
            const int s = wv*16 + (lane >> 4)*4 + r;
            const int i  = ud2[2*s], jn = ud2[2*s+1];
            const float v = acc2[r] + b2;
            Ub[(size_t)(4*i  + p)*512 + 4*jn + q] = v;
            Ub[(size_t)(4*jn + p)*512 + 4*i  + q] = v;
        }
    }
}

// ---------------------------------------------------------------------------
extern "C" void kernel_launch(void* const* d_in, const int* in_sizes, int n_in,
                              void* d_out, int out_size, void* d_ws, size_t ws_size,
                              hipStream_t stream)
{
    const float* x   = (const float*)d_in[0];
    const int*   ud  = (const int*)  d_in[3];
    const float* Wg0 = (const float*)d_in[4];
    const float* bg0 = (const float*)d_in[5];
    const float* Wg1 = (const float*)d_in[6];
    const float* bg1 = (const float*)d_in[7];
    const float* Wg2 = (const float*)d_in[8];
    const float* bg2 = (const float*)d_in[9];
    const float* Wn0 = (const float*)d_in[10];
    const float* bn0 = (const float*)d_in[11];
    const float* Wn1 = (const float*)d_in[12];
    const float* bn1 = (const float*)d_in[13];
    const float* Wn2 = (const float*)d_in[14];
    const float* bn2 = (const float*)d_in[15];
    const float* We0 = (const float*)d_in[16];
    const float* be0 = (const float*)d_in[17];
    const float* We1 = (const float*)d_in[18];
    const float* be1 = (const float*)d_in[19];
    const float* We2 = (const float*)d_in[20];
    const float* be2 = (const float*)d_in[21];

    float* hout = (float*)d_out;                 // (16384, 64) == xb
    float* U    = (float*)d_out + 1048576;       // (128, 512, 512)
    float* Aw   = (float*)d_ws;                  // (16384, 128)
    float* Bw   = Aw + (size_t)16384*128;        // (16384, 128)
    ushort_t* BH  = (ushort_t*)((char*)d_ws + (size_t)2*16384*128*4);
    ushort_t* BM  = BH + 16384;
    ushort_t* W2H = BM + 16384;
    ushort_t* W2M = W2H + 2048;

    k_gcn<<<dim3(128), dim3(128), 0, stream>>>(x, Wg0,bg0, Wg1,bg1, Wg2,bg2, hout);
    k_prep<<<dim3(72), dim3(256), 0, stream>>>(We1, We2, BH, BM, W2H, W2M);
    k_ab<<<dim3(1024), dim3(128), 0, stream>>>(hout, We0, Aw, Bw);
    k_edge<<<dim3(128*127), dim3(256), 0, stream>>>(Aw, Bw, ud, be0,
                                                    BH, BM, be1, W2H, W2M, be2, U);
    k_nodemlp<<<dim3(4096), dim3(256), 0, stream>>>(hout, Wn0,bn0, Wn1,bn1, Wn2,bn2, U);
}